// Round 6
// baseline (504.054 us; speedup 1.0000x reference)
//
#include <hip/hip_runtime.h>

#define DIM 128
#define NG 64
#define NCLS 10
#define CAP 64             // padded-CSR slots per node; P(deg>=64 | lambda=16) ~ 2e-13
#define WSZ 256            // nodes per window (dst/src bucketing granularity)
#define NWMAX 512          // max windows (n <= 131072)
#define CAPB 8192          // edges per window bucket (mean 4096, +64 sigma)
#define EPB 8192           // edges per bucket_kernel block

typedef __attribute__((ext_vector_type(8))) short s8v;
typedef __attribute__((ext_vector_type(4))) float f4v;

__device__ inline unsigned short f2bf(float f) {
    unsigned int u = __float_as_uint(f);
    unsigned int r = (u + 0x7fffu + ((u >> 16) & 1u)) >> 16;
    return (unsigned short)r;
}
__device__ inline unsigned int pack2bf(float a, float b) {
    return ((unsigned int)f2bf(b) << 16) | (unsigned int)f2bf(a);
}

// ---------------- cursor init: curD/curS[w] = w*CAPB ----------------
__global__ void init_cursors(int* curD, int* curS, int nw) {
    int t = blockIdx.x * 256 + threadIdx.x;
    if (t < nw) {
        curD[t] = t * CAPB;
        curS[t] = t * CAPB;
    }
}

// ---------------- Phase A: bucket edges by dst>>8 (packed) and src>>8 (byte) ----------------
// Per-edge path uses ONLY LDS atomics; global atomics are 2*nw per block (range reserve).
__global__ __launch_bounds__(256) void bucket_kernel(const int* __restrict__ src,
                                                     const int* __restrict__ dst,
                                                     int* curD, int* curS,
                                                     int* __restrict__ bucketD,
                                                     unsigned char* __restrict__ bucketS,
                                                     int e, int nw) {
    __shared__ int histD[NWMAX];
    __shared__ int histS[NWMAX];
    int t = threadIdx.x;
    for (int i = t; i < nw; i += 256) { histD[i] = 0; histS[i] = 0; }
    __syncthreads();
    int lo = blockIdx.x * EPB;
    int hi = min(e, lo + EPB);
    for (int i = lo + t * 4; i < hi; i += 1024) {
        int4 d4 = *(const int4*)&dst[i];
        int4 s4 = *(const int4*)&src[i];
        atomicAdd(&histD[d4.x >> 8], 1); atomicAdd(&histS[s4.x >> 8], 1);
        atomicAdd(&histD[d4.y >> 8], 1); atomicAdd(&histS[s4.y >> 8], 1);
        atomicAdd(&histD[d4.z >> 8], 1); atomicAdd(&histS[s4.z >> 8], 1);
        atomicAdd(&histD[d4.w >> 8], 1); atomicAdd(&histS[s4.w >> 8], 1);
    }
    __syncthreads();
    for (int i = t; i < nw; i += 256) {
        int hd = histD[i], hs = histS[i];
        histD[i] = hd ? atomicAdd(&curD[i], hd) : 0;
        histS[i] = hs ? atomicAdd(&curS[i], hs) : 0;
    }
    __syncthreads();
    for (int i = lo + t * 4; i < hi; i += 1024) {
        int4 d4 = *(const int4*)&dst[i];
        int4 s4 = *(const int4*)&src[i];
#pragma unroll
        for (int j = 0; j < 4; ++j) {
            int d = (&d4.x)[j], s = (&s4.x)[j];
            int sd = atomicAdd(&histD[d >> 8], 1);
            bucketD[sd] = (s << 8) | (d & 255);
            int ss = atomicAdd(&histS[s >> 8], 1);
            bucketS[ss] = (unsigned char)(s & 255);
        }
    }
}

// ---------------- Phase B: per-window CSR fill + degrees + rs factors ----------------
__global__ __launch_bounds__(256) void window_kernel(const int* __restrict__ curD,
                                                     const int* __restrict__ curS,
                                                     const int* __restrict__ bucketD,
                                                     const unsigned char* __restrict__ bucketS,
                                                     int* __restrict__ cnt_in,
                                                     float* __restrict__ rs_in,
                                                     float* __restrict__ rs_out,
                                                     int* __restrict__ colx_pad, int n) {
    __shared__ int cin[WSZ];
    __shared__ int cout[WSZ];
    int w = blockIdx.x, t = threadIdx.x;
    cin[t] = 0;
    cout[t] = 0;
    __syncthreads();
    int base = w * CAPB;
    int nE = min(curD[w] - base, CAPB);
    for (int i = t; i < nE; i += 256) {
        int v = bucketD[base + i];
        int d8 = v & 255;
        int slot = atomicAdd(&cin[d8], 1);
        if (slot < CAP) colx_pad[(((w << 8) + d8) << 6) + slot] = v >> 8;
    }
    int nS = min(curS[w] - base, CAPB);
    for (int i = t; i < nS; i += 256) atomicAdd(&cout[bucketS[base + i]], 1);
    __syncthreads();
    int node = (w << 8) + t;
    if (node < n) {
        int c = cin[t];
        cnt_in[node] = c;
        rs_in[node] = rsqrtf(fmaxf((float)c, 1.0f));
        rs_out[node] = rsqrtf(fmaxf((float)cout[t], 1.0f));
    }
}

// ---------------- cast f32 rows -> packed bf16 rows, pre-scaled by rs_out[node] ----------------
__global__ void cast_scale_kernel(const float* __restrict__ x, const float* __restrict__ rs_out,
                                  unsigned int* __restrict__ y, int total2) {
    int i = blockIdx.x * 256 + threadIdx.x;
    if (i < total2) {
        float s = rs_out[i >> 6];
        float2 v = ((const float2*)x)[i];
        y[i] = pack2bf(v.x * s, v.y * s);
    }
}

// ---------------- cast + transpose W[128][128] f32 -> Wt bf16, Wt[c][k]=W[k][c] ----------------
__global__ void cast_wt_kernel(const float* __restrict__ W, unsigned short* __restrict__ Wt) {
    int t = blockIdx.x * 256 + threadIdx.x;   // 16384 total
    int c = t >> 7, k = t & 127;
    Wt[t] = f2bf(W[k * 128 + c]);
}

// ---------------- FUSED layer: SpMM gather -> LDS tile -> MFMA -> epilogue ----------------
// Block = 4 waves x 16 nodes. Wave gathers its 16 node-rows (pre-scaled bf16 table) into a
// wave-private LDS tile (row stride 68 words -> only 2-way bank aliasing), then MFMA vs Wt.
// LAYER2=0: epilogue stores bf16 rows pre-scaled by rs_out (feeds next gather).
// LAYER2=1: epilogue fuses mean-readout numerator: relu rows accumulate into LDS hgloc
//           (gid sorted -> block spans <=2 graphs typ.) then ~512 global atomics/block.
template <int LAYER2>
__global__ __launch_bounds__(256) void fused_layer(const unsigned int* __restrict__ xb,
                                                   const int* __restrict__ cnt_in,
                                                   const int* __restrict__ colx_pad,
                                                   const float* __restrict__ rs_in,
                                                   const unsigned char* __restrict__ Wt,
                                                   const float* __restrict__ bias,
                                                   const float* __restrict__ rs_out,
                                                   unsigned int* __restrict__ yb,
                                                   const int* __restrict__ gid,
                                                   float* __restrict__ hg, int n) {
    __shared__ unsigned int agg[4][16][68];   // 17.4 KB, wave-private tiles
    __shared__ float hgloc[4][DIM];           // layer2 readout accumulator
    int wave = threadIdx.x >> 6, lane = threadIdx.x & 63;
    int m = lane & 15, q = lane >> 4;
    int r0 = blockIdx.x * 64 + wave * 16;
    int gid0 = 0;
    if (LAYER2) {
        for (int i = threadIdx.x; i < 4 * DIM; i += 256) ((float*)hgloc)[i] = 0.0f;
        gid0 = gid[blockIdx.x * 64];
    }
    // ---- gather phase: 16 nodes per wave ----
    for (int i = 0; i < 16; ++i) {
        int node = min(r0 + i, n - 1);
        int cnt = min(cnt_in[node], CAP);
        int myc = colx_pad[(node << 6) + ((lane < cnt) ? lane : 0)];
        float ax = 0.0f, ay = 0.0f;
        int j = 0;
        for (; j + 8 <= cnt; j += 8) {
            unsigned int v[8];
#pragma unroll
            for (int p = 0; p < 8; ++p) {
                int c = __shfl(myc, j + p);
                v[p] = xb[(size_t)c * 64 + lane];
            }
#pragma unroll
            for (int p = 0; p < 8; ++p) {
                ax += __uint_as_float(v[p] << 16);
                ay += __uint_as_float(v[p] & 0xffff0000u);
            }
        }
        for (; j < cnt; ++j) {
            int c = __shfl(myc, j);
            unsigned int v = xb[(size_t)c * 64 + lane];
            ax += __uint_as_float(v << 16);
            ay += __uint_as_float(v & 0xffff0000u);
        }
        float w = rs_in[node];
        agg[wave][i][lane] = pack2bf(ax * w, ay * w);
    }
    __syncthreads();   // orders LDS agg writes before cross-lane A-frag reads (and hgloc init)
    // ---- MFMA phase: A-frag A[m][k0*32+q*8+j] from LDS, B from L1-hot Wt ----
    f4v acc[8];
#pragma unroll
    for (int c = 0; c < 8; ++c) acc[c] = (f4v){0.f, 0.f, 0.f, 0.f};
#pragma unroll
    for (int k0 = 0; k0 < 4; ++k0) {
        s8v a = *(const s8v*)&agg[wave][m][k0 * 16 + q * 4];
#pragma unroll
        for (int c = 0; c < 8; ++c) {
            s8v b = *(const s8v*)(Wt + (size_t)(c * 16 + m) * 256 + k0 * 64 + q * 16);
            acc[c] = __builtin_amdgcn_mfma_f32_16x16x32_bf16(a, b, acc[c], 0, 0, 0);
        }
    }
    // ---- epilogue: C/D layout col=lane&15 (as m), row=q*4+r ----
    if (!LAYER2) {
#pragma unroll
        for (int c = 0; c < 8; ++c) {
            float bv = bias[c * 16 + m];
#pragma unroll
            for (int r = 0; r < 4; ++r) {
                int row = r0 + q * 4 + r;
                if (row < n) {
                    float val = fmaxf(acc[c][r] + bv, 0.0f);
                    ((unsigned short*)yb)[(size_t)row * 128 + c * 16 + m] =
                        f2bf(val * rs_out[row]);
                }
            }
        }
    } else {
#pragma unroll
        for (int r = 0; r < 4; ++r) {
            int row = r0 + q * 4 + r;
            if (row < n) {
                int g = gid[row];
                int gl = g - gid0;
#pragma unroll
                for (int c = 0; c < 8; ++c) {
                    float val = fmaxf(acc[c][r] + bias[c * 16 + m], 0.0f);
                    if (gl < 4)
                        atomicAdd(&hgloc[gl][c * 16 + m], val);
                    else
                        atomicAdd(&hg[(size_t)g * DIM + c * 16 + m], val);
                }
            }
        }
        __syncthreads();
        for (int i = threadIdx.x; i < 4 * DIM; i += 256) {
            float v = ((float*)hgloc)[i];
            if (v != 0.0f) atomicAdd(&hg[(size_t)(gid0 + (i >> 7)) * DIM + (i & 127)], v);
        }
    }
}

// ---------------- per-graph node counts via binary search (gid sorted) ----------------
__global__ void gcount_kernel(const int* __restrict__ gid, int* __restrict__ gcount, int n) {
    int g = threadIdx.x;   // 64 threads
    if (g >= NG) return;
    int lo = 0, hi = n;
    while (lo < hi) { int mid = (lo + hi) >> 1; if (gid[mid] < g) lo = mid + 1; else hi = mid; }
    int lb = lo;
    lo = 0; hi = n;
    while (lo < hi) { int mid = (lo + hi) >> 1; if (gid[mid] <= g) lo = mid + 1; else hi = mid; }
    gcount[g] = lo - lb;
}

// ---------------- classifier ----------------
__global__ void classify_kernel(const float* __restrict__ hg, const int* __restrict__ gcount,
                                const float* __restrict__ Wc, const float* __restrict__ bc,
                                float* __restrict__ out) {
    int t = blockIdx.x * 256 + threadIdx.x;
    if (t >= NG * NCLS) return;
    int g = t / NCLS, c = t % NCLS;
    float inv = 1.0f / fmaxf((float)gcount[g], 1.0f);
    float s = 0.0f;
    for (int k = 0; k < DIM; ++k) s = fmaf(hg[g * DIM + k], Wc[k * NCLS + c], s);
    out[t] = s * inv + bc[c];
}

extern "C" void kernel_launch(void* const* d_in, const int* in_sizes, int n_in,
                              void* d_out, int out_size, void* d_ws, size_t ws_size,
                              hipStream_t stream) {
    const float* h   = (const float*)d_in[0];
    const int*   src = (const int*)d_in[1];
    const int*   dst = (const int*)d_in[2];
    const int*   gid = (const int*)d_in[3];
    const float* W1  = (const float*)d_in[4];
    const float* b1  = (const float*)d_in[5];
    const float* W2  = (const float*)d_in[6];
    const float* b2  = (const float*)d_in[7];
    const float* Wc  = (const float*)d_in[8];
    const float* bc  = (const float*)d_in[9];
    float* out = (float*)d_out;

    const int n = in_sizes[0] / DIM;   // 100000
    const int e = in_sizes[1];         // 1600000
    const int nw = (n + WSZ - 1) / WSZ;   // 391 windows

    // workspace layout (256B aligned)
    char* ws = (char*)d_ws;
    size_t off = 0;
    auto alloc = [&](size_t bytes) -> char* {
        char* p = ws + off;
        off = (off + bytes + 255) & ~(size_t)255;
        return p;
    };
    int*   cnt_in  = (int*)alloc((size_t)n * 4);
    float* rs_in   = (float*)alloc((size_t)n * 4);
    float* rs_out  = (float*)alloc((size_t)n * 4);
    int*   curD    = (int*)alloc((size_t)NWMAX * 4);
    int*   curS    = (int*)alloc((size_t)NWMAX * 4);
    int*   colx_pad = (int*)alloc((size_t)n * CAP * 4);          // 25.6 MB
    int*   bucketD = (int*)alloc((size_t)nw * CAPB * 4);         // 12.8 MB
    unsigned char* bucketS = (unsigned char*)alloc((size_t)nw * CAPB);  // 3.2 MB
    float* hg      = (float*)alloc((size_t)NG * DIM * 4);
    int*   gcount  = (int*)alloc(NG * 4);
    unsigned short* Wt1 = (unsigned short*)alloc(128 * 128 * 2);
    unsigned short* Wt2 = (unsigned short*)alloc(128 * 128 * 2);
    unsigned int* hb  = (unsigned int*)alloc((size_t)n * 64 * 4);   // bf16 of h (pre-scaled)
    unsigned int* x1b = (unsigned int*)alloc((size_t)n * 64 * 4);   // layer1 out (pre-scaled)

    const int MM_B = (n + 63) / 64;
    const int C2 = n * 64;   // uints in a bf16 feature table
    const int AB = (e + EPB - 1) / EPB;

    hipMemsetAsync(hg, 0, (size_t)NG * DIM * 4, stream);

    // bucketed build: per-edge work uses only LDS atomics
    init_cursors<<<(nw + 255) / 256, 256, 0, stream>>>(curD, curS, nw);
    bucket_kernel<<<AB, 256, 0, stream>>>(src, dst, curD, curS, bucketD, bucketS, e, nw);
    window_kernel<<<nw, 256, 0, stream>>>(curD, curS, bucketD, bucketS,
                                          cnt_in, rs_in, rs_out, colx_pad, n);

    // weight prep + pre-scaled bf16 feature table
    cast_wt_kernel<<<64, 256, 0, stream>>>(W1, Wt1);
    cast_wt_kernel<<<64, 256, 0, stream>>>(W2, Wt2);
    cast_scale_kernel<<<(C2 + 255) / 256, 256, 0, stream>>>(h, rs_out, hb, C2);

    // layer 1: gather + MFMA + bf16 store (pre-scaled by rs_out)
    fused_layer<0><<<MM_B, 256, 0, stream>>>(hb, cnt_in, colx_pad, rs_in,
                                             (const unsigned char*)Wt1, b1, rs_out,
                                             x1b, nullptr, nullptr, n);
    // layer 2: gather + MFMA + fused mean-readout numerator
    fused_layer<1><<<MM_B, 256, 0, stream>>>(x1b, cnt_in, colx_pad, rs_in,
                                             (const unsigned char*)Wt2, b2, nullptr,
                                             nullptr, gid, hg, n);
    // counts + classify
    gcount_kernel<<<1, 64, 0, stream>>>(gid, gcount, n);
    classify_kernel<<<(NG * NCLS + 255) / 256, 256, 0, stream>>>(hg, gcount, Wc, bc, out);
}

// Round 8
// 386.669 us; speedup vs baseline: 1.3036x; 1.3036x over previous
//
#include <hip/hip_runtime.h>

#define DIM 128
#define NG 64
#define NCLS 10
#define CAP 64             // padded-CSR slots per node; P(deg>=64 | lambda=16) ~ 2e-13
#define WSZ 256            // nodes per window (dst/src bucketing granularity)
#define NWMAX 512          // max windows (n <= 131072)
#define CAPB 8192          // edges per window bucket (mean 4096, +64 sigma)
#define EPB 8192           // edges per bucket_kernel block
#define HL 4               // local readout accumulator graphs per block

typedef __attribute__((ext_vector_type(8))) short s8v;
typedef __attribute__((ext_vector_type(4))) float f4v;

__device__ inline unsigned short f2bf(float f) {
    unsigned int u = __float_as_uint(f);
    unsigned int r = (u + 0x7fffu + ((u >> 16) & 1u)) >> 16;
    return (unsigned short)r;
}
__device__ inline unsigned int pack2bf(float a, float b) {
    return ((unsigned int)f2bf(b) << 16) | (unsigned int)f2bf(a);
}

// ---------------- cursor init: curD/curS[w] = w*CAPB ----------------
__global__ void init_cursors(int* curD, int* curS, int nw) {
    int t = blockIdx.x * 256 + threadIdx.x;
    if (t < nw) {
        curD[t] = t * CAPB;
        curS[t] = t * CAPB;
    }
}

// ---------------- Phase A: bucket edges by dst>>8 (packed) and src>>8 (byte) ----------------
// Per-edge path uses ONLY LDS atomics; global atomics are 2*nw per block (range reserve).
__global__ __launch_bounds__(256) void bucket_kernel(const int* __restrict__ src,
                                                     const int* __restrict__ dst,
                                                     int* curD, int* curS,
                                                     int* __restrict__ bucketD,
                                                     unsigned char* __restrict__ bucketS,
                                                     int e, int nw) {
    __shared__ int histD[NWMAX];
    __shared__ int histS[NWMAX];
    int t = threadIdx.x;
    for (int i = t; i < nw; i += 256) { histD[i] = 0; histS[i] = 0; }
    __syncthreads();
    int lo = blockIdx.x * EPB;
    int hi = min(e, lo + EPB);
    for (int i = lo + t * 4; i < hi; i += 1024) {
        int4 d4 = *(const int4*)&dst[i];
        int4 s4 = *(const int4*)&src[i];
        atomicAdd(&histD[d4.x >> 8], 1); atomicAdd(&histS[s4.x >> 8], 1);
        atomicAdd(&histD[d4.y >> 8], 1); atomicAdd(&histS[s4.y >> 8], 1);
        atomicAdd(&histD[d4.z >> 8], 1); atomicAdd(&histS[s4.z >> 8], 1);
        atomicAdd(&histD[d4.w >> 8], 1); atomicAdd(&histS[s4.w >> 8], 1);
    }
    __syncthreads();
    for (int i = t; i < nw; i += 256) {
        int hd = histD[i], hs = histS[i];
        histD[i] = hd ? atomicAdd(&curD[i], hd) : 0;
        histS[i] = hs ? atomicAdd(&curS[i], hs) : 0;
    }
    __syncthreads();
    for (int i = lo + t * 4; i < hi; i += 1024) {
        int4 d4 = *(const int4*)&dst[i];
        int4 s4 = *(const int4*)&src[i];
#pragma unroll
        for (int j = 0; j < 4; ++j) {
            int d = (&d4.x)[j], s = (&s4.x)[j];
            int sd = atomicAdd(&histD[d >> 8], 1);
            bucketD[sd] = (s << 8) | (d & 255);
            int ss = atomicAdd(&histS[s >> 8], 1);
            bucketS[ss] = (unsigned char)(s & 255);
        }
    }
}

// ---------------- Phase B: per-window CSR fill + degrees + rs factors ----------------
__global__ __launch_bounds__(256) void window_kernel(const int* __restrict__ curD,
                                                     const int* __restrict__ curS,
                                                     const int* __restrict__ bucketD,
                                                     const unsigned char* __restrict__ bucketS,
                                                     int* __restrict__ cnt_in,
                                                     float* __restrict__ rs_in,
                                                     float* __restrict__ rs_out,
                                                     int* __restrict__ colx_pad, int n) {
    __shared__ int cin[WSZ];
    __shared__ int cout[WSZ];
    int w = blockIdx.x, t = threadIdx.x;
    cin[t] = 0;
    cout[t] = 0;
    __syncthreads();
    int base = w * CAPB;
    int nE = min(curD[w] - base, CAPB);
    for (int i = t; i < nE; i += 256) {
        int v = bucketD[base + i];
        int d8 = v & 255;
        int slot = atomicAdd(&cin[d8], 1);
        if (slot < CAP) colx_pad[(((w << 8) + d8) << 6) + slot] = v >> 8;
    }
    int nS = min(curS[w] - base, CAPB);
    for (int i = t; i < nS; i += 256) atomicAdd(&cout[bucketS[base + i]], 1);
    __syncthreads();
    int node = (w << 8) + t;
    if (node < n) {
        int c = cin[t];
        cnt_in[node] = c;
        rs_in[node] = rsqrtf(fmaxf((float)c, 1.0f));
        rs_out[node] = rsqrtf(fmaxf((float)cout[t], 1.0f));
    }
}

// ---------------- cast f32 rows -> packed bf16 rows, pre-scaled by rs_out[node] ----------------
__global__ void cast_scale_kernel(const float* __restrict__ x, const float* __restrict__ rs_out,
                                  unsigned int* __restrict__ y, int total2) {
    int i = blockIdx.x * 256 + threadIdx.x;
    if (i < total2) {
        float s = rs_out[i >> 6];
        float2 v = ((const float2*)x)[i];
        y[i] = pack2bf(v.x * s, v.y * s);
    }
}

// ---------------- cast + transpose BOTH weight matrices in one launch ----------------
__global__ void cast_wt2_kernel(const float* __restrict__ W1, const float* __restrict__ W2,
                                unsigned short* __restrict__ Wt1,
                                unsigned short* __restrict__ Wt2) {
    int t = blockIdx.x * 256 + threadIdx.x;   // 32768 total
    int which = t >> 14;
    int i = t & 16383;
    int c = i >> 7, k = i & 127;
    const float* W = which ? W2 : W1;
    unsigned short* Wt = which ? Wt2 : Wt1;
    Wt[i] = f2bf(W[k * 128 + c]);
}

// ---------------- SpMM gather (pre-scaled bf16 table, padded CSR), 16-deep pipeline ------------
// One wave per node; all <=64 col indices in one vector load, broadcast via __shfl (v_readlane).
// NO LDS, low VGPR: occupancy is what feeds the latency-bound gather.
__global__ __launch_bounds__(256) void spmm_bf16(const unsigned int* __restrict__ xb,
                                                 const int* __restrict__ cnt_in,
                                                 const int* __restrict__ colx_pad,
                                                 const float* __restrict__ rs_in,
                                                 unsigned int* __restrict__ yb, int n) {
    int node = (blockIdx.x * 256 + threadIdx.x) >> 6;
    int lane = threadIdx.x & 63;
    if (node >= n) return;
    int cnt = min(cnt_in[node], CAP);
    int myc = colx_pad[(node << 6) + ((lane < cnt) ? lane : 0)];
    float ax = 0.0f, ay = 0.0f;
    int j = 0;
    for (; j + 16 <= cnt; j += 16) {
        unsigned int v[16];
#pragma unroll
        for (int q = 0; q < 16; ++q) {
            int c = __shfl(myc, j + q);
            v[q] = xb[(size_t)c * 64 + lane];
        }
#pragma unroll
        for (int q = 0; q < 16; ++q) {
            ax += __uint_as_float(v[q] << 16);
            ay += __uint_as_float(v[q] & 0xffff0000u);
        }
    }
    for (; j + 8 <= cnt; j += 8) {
        unsigned int v[8];
#pragma unroll
        for (int q = 0; q < 8; ++q) {
            int c = __shfl(myc, j + q);
            v[q] = xb[(size_t)c * 64 + lane];
        }
#pragma unroll
        for (int q = 0; q < 8; ++q) {
            ax += __uint_as_float(v[q] << 16);
            ay += __uint_as_float(v[q] & 0xffff0000u);
        }
    }
    for (; j < cnt; ++j) {
        int c = __shfl(myc, j);
        unsigned int v = xb[(size_t)c * 64 + lane];
        ax += __uint_as_float(v << 16);
        ay += __uint_as_float(v & 0xffff0000u);
    }
    float w = rs_in[node];
    yb[(size_t)node * 64 + lane] = pack2bf(ax * w, ay * w);
}

// ---------------- layer-1 MM: x1b = bf16( relu(A@W1+b1) * rs_out[row] ) ----------------
// A-frag: A[m=lane&15][k0*32+q*8+j]; C/D: col=lane&15, row=q*4+reg (guide §3, m89-verified)
__global__ __launch_bounds__(256) void mm_mfma(const unsigned char* __restrict__ A,
                                               const unsigned char* __restrict__ Wt,
                                               const float* __restrict__ bias,
                                               const float* __restrict__ rs_out,
                                               unsigned short* __restrict__ out, int n) {
    int wave = threadIdx.x >> 6, lane = threadIdx.x & 63;
    int m = lane & 15, q = lane >> 4;
    int r0 = (int)blockIdx.x * 64 + wave * 16;
    int arow = min(r0 + m, n - 1);
    f4v acc[8];
#pragma unroll
    for (int c = 0; c < 8; ++c) acc[c] = (f4v){0.f, 0.f, 0.f, 0.f};
#pragma unroll
    for (int k0 = 0; k0 < 4; ++k0) {
        s8v a = *(const s8v*)(A + (size_t)arow * 256 + k0 * 64 + q * 16);
#pragma unroll
        for (int c = 0; c < 8; ++c) {
            s8v b = *(const s8v*)(Wt + (size_t)(c * 16 + m) * 256 + k0 * 64 + q * 16);
            acc[c] = __builtin_amdgcn_mfma_f32_16x16x32_bf16(a, b, acc[c], 0, 0, 0);
        }
    }
#pragma unroll
    for (int c = 0; c < 8; ++c) {
        float bv = bias[c * 16 + m];
#pragma unroll
        for (int r = 0; r < 4; ++r) {
            int row = r0 + q * 4 + r;
            if (row < n) {
                float val = fmaxf(acc[c][r] + bv, 0.0f);
                out[(size_t)row * 128 + c * 16 + m] = f2bf(val * rs_out[row]);
            }
        }
    }
}

// ---------------- layer-2 MM with FUSED mean-readout numerator ----------------
// Never materializes layer-2 features. Per-wave: if all 16 rows share one graph (common,
// gid sorted), reduce relu rows in-register (r) then across q-lanes (shfl_xor 16/32) ->
// one LDS atomic per (c,m) from q==0. Block-level LDS accumulator flushed with ~256
// global atomics. No LDS in the MFMA path itself; occupancy unaffected (A read global).
__global__ __launch_bounds__(256) void mm_mfma_readout(const unsigned char* __restrict__ A,
                                                       const unsigned char* __restrict__ Wt,
                                                       const float* __restrict__ bias,
                                                       const int* __restrict__ gid,
                                                       float* __restrict__ hg, int n) {
    __shared__ float hgloc[HL][DIM];
    int wave = threadIdx.x >> 6, lane = threadIdx.x & 63;
    int m = lane & 15, q = lane >> 4;
    int r0 = (int)blockIdx.x * 64 + wave * 16;
    int b0 = (int)blockIdx.x * 64;
    int gid0 = gid[min(b0, n - 1)];
    for (int i = threadIdx.x; i < HL * DIM; i += 256) ((float*)hgloc)[i] = 0.0f;
    __syncthreads();
    int arow = min(r0 + m, n - 1);
    f4v acc[8];
#pragma unroll
    for (int c = 0; c < 8; ++c) acc[c] = (f4v){0.f, 0.f, 0.f, 0.f};
#pragma unroll
    for (int k0 = 0; k0 < 4; ++k0) {
        s8v a = *(const s8v*)(A + (size_t)arow * 256 + k0 * 64 + q * 16);
#pragma unroll
        for (int c = 0; c < 8; ++c) {
            s8v b = *(const s8v*)(Wt + (size_t)(c * 16 + m) * 256 + k0 * 64 + q * 16);
            acc[c] = __builtin_amdgcn_mfma_f32_16x16x32_bf16(a, b, acc[c], 0, 0, 0);
        }
    }
    // epilogue
    int gfirst = gid[min(r0, n - 1)];
    int glast = gid[min(r0 + 15, n - 1)];
    bool uni = (gfirst == glast) && (r0 + 15 < n);
    if (uni) {
        int gl = gfirst - gid0;   // 0 <= gl (sorted); typically < HL
#pragma unroll
        for (int c = 0; c < 8; ++c) {
            float bv = bias[c * 16 + m];
            float s = fmaxf(acc[c][0] + bv, 0.0f) + fmaxf(acc[c][1] + bv, 0.0f) +
                      fmaxf(acc[c][2] + bv, 0.0f) + fmaxf(acc[c][3] + bv, 0.0f);
            s += __shfl_xor(s, 16);
            s += __shfl_xor(s, 32);
            if (q == 0) {
                if (gl < HL)
                    atomicAdd(&hgloc[gl][c * 16 + m], s);
                else
                    atomicAdd(&hg[(size_t)gfirst * DIM + c * 16 + m], s);
            }
        }
    } else {
#pragma unroll
        for (int r = 0; r < 4; ++r) {
            int row = r0 + q * 4 + r;
            if (row < n) {
                int g = gid[row];
                int gl = g - gid0;
#pragma unroll
                for (int c = 0; c < 8; ++c) {
                    float val = fmaxf(acc[c][r] + bias[c * 16 + m], 0.0f);
                    if (gl < HL)
                        atomicAdd(&hgloc[gl][c * 16 + m], val);
                    else
                        atomicAdd(&hg[(size_t)g * DIM + c * 16 + m], val);
                }
            }
        }
    }
    __syncthreads();
    for (int i = threadIdx.x; i < HL * DIM; i += 256) {
        float v = ((float*)hgloc)[i];
        int g = gid0 + (i >> 7);
        if (v != 0.0f && g < NG) atomicAdd(&hg[(size_t)g * DIM + (i & 127)], v);
    }
}

// ---------------- classifier with fused per-graph counts (gid sorted -> binary search) --------
__global__ void classify_kernel(const float* __restrict__ hg, const int* __restrict__ gid,
                                const float* __restrict__ Wc, const float* __restrict__ bc,
                                float* __restrict__ out, int n) {
    __shared__ float inv[NG];
    int t = threadIdx.x;
    if (t < NG) {
        int g = t;
        int lo = 0, hi = n;
        while (lo < hi) { int mid = (lo + hi) >> 1; if (gid[mid] < g) lo = mid + 1; else hi = mid; }
        int lb = lo;
        lo = 0; hi = n;
        while (lo < hi) { int mid = (lo + hi) >> 1; if (gid[mid] <= g) lo = mid + 1; else hi = mid; }
        inv[t] = 1.0f / fmaxf((float)(lo - lb), 1.0f);
    }
    __syncthreads();
    for (int idx = t; idx < NG * NCLS; idx += 256) {
        int g = idx / NCLS, c = idx % NCLS;
        float s = 0.0f;
        for (int k = 0; k < DIM; ++k) s = fmaf(hg[g * DIM + k], Wc[k * NCLS + c], s);
        out[idx] = s * inv[g] + bc[c];
    }
}

extern "C" void kernel_launch(void* const* d_in, const int* in_sizes, int n_in,
                              void* d_out, int out_size, void* d_ws, size_t ws_size,
                              hipStream_t stream) {
    const float* h   = (const float*)d_in[0];
    const int*   src = (const int*)d_in[1];
    const int*   dst = (const int*)d_in[2];
    const int*   gid = (const int*)d_in[3];
    const float* W1  = (const float*)d_in[4];
    const float* b1  = (const float*)d_in[5];
    const float* W2  = (const float*)d_in[6];
    const float* b2  = (const float*)d_in[7];
    const float* Wc  = (const float*)d_in[8];
    const float* bc  = (const float*)d_in[9];
    float* out = (float*)d_out;

    const int n = in_sizes[0] / DIM;   // 100000
    const int e = in_sizes[1];         // 1600000
    const int nw = (n + WSZ - 1) / WSZ;   // 391 windows

    // workspace layout (256B aligned)
    char* ws = (char*)d_ws;
    size_t off = 0;
    auto alloc = [&](size_t bytes) -> char* {
        char* p = ws + off;
        off = (off + bytes + 255) & ~(size_t)255;
        return p;
    };
    int*   cnt_in  = (int*)alloc((size_t)n * 4);
    float* rs_in   = (float*)alloc((size_t)n * 4);
    float* rs_out  = (float*)alloc((size_t)n * 4);
    int*   curD    = (int*)alloc((size_t)NWMAX * 4);
    int*   curS    = (int*)alloc((size_t)NWMAX * 4);
    int*   colx_pad = (int*)alloc((size_t)n * CAP * 4);          // 25.6 MB
    int*   bucketD = (int*)alloc((size_t)nw * CAPB * 4);         // 12.8 MB
    unsigned char* bucketS = (unsigned char*)alloc((size_t)nw * CAPB);  // 3.2 MB
    float* hg      = (float*)alloc((size_t)NG * DIM * 4);
    unsigned short* Wt1 = (unsigned short*)alloc(128 * 128 * 2);
    unsigned short* Wt2 = (unsigned short*)alloc(128 * 128 * 2);
    unsigned int* hb   = (unsigned int*)alloc((size_t)n * 64 * 4);  // bf16 h (pre-scaled)
    unsigned int* aggB = (unsigned int*)alloc((size_t)n * 64 * 4);  // spmm out (bf16 rows)
    unsigned int* x1b  = (unsigned int*)alloc((size_t)n * 64 * 4);  // mm1 out (pre-scaled)

    const int SPMM_B = (n + 3) / 4;
    const int MM_B = (n + 63) / 64;
    const int C2 = n * 64;
    const int AB = (e + EPB - 1) / EPB;

    (void)hipMemsetAsync(hg, 0, (size_t)NG * DIM * 4, stream);

    // bucketed build: per-edge work uses only LDS atomics
    init_cursors<<<(nw + 255) / 256, 256, 0, stream>>>(curD, curS, nw);
    bucket_kernel<<<AB, 256, 0, stream>>>(src, dst, curD, curS, bucketD, bucketS, e, nw);
    window_kernel<<<nw, 256, 0, stream>>>(curD, curS, bucketD, bucketS,
                                          cnt_in, rs_in, rs_out, colx_pad, n);

    // weight prep + pre-scaled bf16 feature table
    cast_wt2_kernel<<<128, 256, 0, stream>>>(W1, W2, Wt1, Wt2);
    cast_scale_kernel<<<(C2 + 255) / 256, 256, 0, stream>>>(h, rs_out, hb, C2);

    // layer 1
    spmm_bf16<<<SPMM_B, 256, 0, stream>>>(hb, cnt_in, colx_pad, rs_in, aggB, n);
    mm_mfma<<<MM_B, 256, 0, stream>>>((const unsigned char*)aggB,
                                      (const unsigned char*)Wt1, b1, rs_out, (unsigned short*)x1b, n);
    // layer 2 + fused readout numerator
    spmm_bf16<<<SPMM_B, 256, 0, stream>>>(x1b, cnt_in, colx_pad, rs_in, aggB, n);
    mm_mfma_readout<<<MM_B, 256, 0, stream>>>((const unsigned char*)aggB,
                                              (const unsigned char*)Wt2, b2, gid, hg, n);
    // classify (fused gcount)
    classify_kernel<<<1, 256, 0, stream>>>(hg, gid, Wc, bc, out, n);
}

// Round 9
// 363.094 us; speedup vs baseline: 1.3882x; 1.0649x over previous
//
#include <hip/hip_runtime.h>

#define DIM 128
#define NG 64
#define NCLS 10
#define CAP 64             // padded-CSR slots per node; P(deg>=64 | lambda=16) ~ 2e-13
#define WSZ 256            // nodes per window (dst/src bucketing granularity)
#define NWMAX 512          // max windows (n <= 131072)
#define CAPB 8192          // edges per window bucket (mean 4096, +64 sigma)
#define EPB 8192           // edges per bucket_kernel block
#define HL 4               // local readout accumulator graphs per block

typedef __attribute__((ext_vector_type(8))) short s8v;
typedef __attribute__((ext_vector_type(4))) float f4v;

__device__ inline unsigned short f2bf(float f) {
    unsigned int u = __float_as_uint(f);
    unsigned int r = (u + 0x7fffu + ((u >> 16) & 1u)) >> 16;
    return (unsigned short)r;
}
__device__ inline unsigned int pack2bf(float a, float b) {
    return ((unsigned int)f2bf(b) << 16) | (unsigned int)f2bf(a);
}

// ---------------- prep: cursors + weight cast/transpose + zero rows ----------------
__global__ void prep_kernel(const float* __restrict__ W1, const float* __restrict__ W2,
                            unsigned short* __restrict__ Wt1, unsigned short* __restrict__ Wt2,
                            int* curD, int* curS, uint4* hb4, uint4* x1b4, int nw, int n) {
    int t = blockIdx.x * 256 + threadIdx.x;
    if (t < nw) {
        curD[t] = t * CAPB;
        curS[t] = t * CAPB;
    }
    if (t < 32768) {
        int which = t >> 14;
        int i = t & 16383;
        int c = i >> 7, k = i & 127;
        (which ? Wt2 : Wt1)[i] = f2bf((which ? W2 : W1)[k * 128 + c]);
    }
    if (t < 16) {   // zero row at index n (gather padding target)
        uint4 z = make_uint4(0, 0, 0, 0);
        hb4[(size_t)n * 16 + t] = z;
        x1b4[(size_t)n * 16 + t] = z;
    }
}

// ---------------- Phase A: bucket edges by dst>>8 (packed) and src>>8 (byte) ----------------
// Per-edge path uses ONLY LDS atomics; global atomics are 2*nw per block (range reserve).
__global__ __launch_bounds__(256) void bucket_kernel(const int* __restrict__ src,
                                                     const int* __restrict__ dst,
                                                     int* curD, int* curS,
                                                     int* __restrict__ bucketD,
                                                     unsigned char* __restrict__ bucketS,
                                                     int e, int nw) {
    __shared__ int histD[NWMAX];
    __shared__ int histS[NWMAX];
    int t = threadIdx.x;
    for (int i = t; i < nw; i += 256) { histD[i] = 0; histS[i] = 0; }
    __syncthreads();
    int lo = blockIdx.x * EPB;
    int hi = min(e, lo + EPB);
    for (int i = lo + t * 4; i < hi; i += 1024) {
        int4 d4 = *(const int4*)&dst[i];
        int4 s4 = *(const int4*)&src[i];
        atomicAdd(&histD[d4.x >> 8], 1); atomicAdd(&histS[s4.x >> 8], 1);
        atomicAdd(&histD[d4.y >> 8], 1); atomicAdd(&histS[s4.y >> 8], 1);
        atomicAdd(&histD[d4.z >> 8], 1); atomicAdd(&histS[s4.z >> 8], 1);
        atomicAdd(&histD[d4.w >> 8], 1); atomicAdd(&histS[s4.w >> 8], 1);
    }
    __syncthreads();
    for (int i = t; i < nw; i += 256) {
        int hd = histD[i], hs = histS[i];
        histD[i] = hd ? atomicAdd(&curD[i], hd) : 0;
        histS[i] = hs ? atomicAdd(&curS[i], hs) : 0;
    }
    __syncthreads();
    for (int i = lo + t * 4; i < hi; i += 1024) {
        int4 d4 = *(const int4*)&dst[i];
        int4 s4 = *(const int4*)&src[i];
#pragma unroll
        for (int j = 0; j < 4; ++j) {
            int d = (&d4.x)[j], s = (&s4.x)[j];
            int sd = atomicAdd(&histD[d >> 8], 1);
            bucketD[sd] = (s << 8) | (d & 255);
            int ss = atomicAdd(&histS[s >> 8], 1);
            bucketS[ss] = (unsigned char)(s & 255);
        }
    }
}

// ---------------- Phase B: window CSR fill + degrees + rs + FUSED h cast ----------------
// Block w owns nodes [w*256, w*256+256). Slot atomics in LDS; colx_pad padded to a
// multiple of 4 slots with zero-row index n (enables dwordx4 gather without tails).
// Also casts h rows -> pre-scaled bf16 table (rs_out is in LDS here anyway).
__global__ __launch_bounds__(256) void window_kernel(const int* __restrict__ curD,
                                                     const int* __restrict__ curS,
                                                     const int* __restrict__ bucketD,
                                                     const unsigned char* __restrict__ bucketS,
                                                     const float* __restrict__ h,
                                                     int* __restrict__ cnt_in,
                                                     float* __restrict__ rs_in,
                                                     float* __restrict__ rs_out,
                                                     int* __restrict__ colx_pad,
                                                     uint4* __restrict__ hb4, int n) {
    __shared__ int cin[WSZ];
    __shared__ int cout[WSZ];
    __shared__ float rsO_s[WSZ];
    int w = blockIdx.x, t = threadIdx.x;
    cin[t] = 0;
    cout[t] = 0;
    __syncthreads();
    int base = w * CAPB;
    int nE = min(curD[w] - base, CAPB);
    for (int i = t; i < nE; i += 256) {
        int v = bucketD[base + i];
        int d8 = v & 255;
        int slot = atomicAdd(&cin[d8], 1);
        if (slot < CAP) colx_pad[(((w << 8) + d8) << 6) + slot] = v >> 8;
    }
    int nS = min(curS[w] - base, CAPB);
    for (int i = t; i < nS; i += 256) atomicAdd(&cout[bucketS[base + i]], 1);
    __syncthreads();
    int node = (w << 8) + t;
    if (node < n) {
        int c = cin[t];
        cnt_in[node] = c;
        rs_in[node] = rsqrtf(fmaxf((float)c, 1.0f));
        float ro = rsqrtf(fmaxf((float)cout[t], 1.0f));
        rs_out[node] = ro;
        rsO_s[t] = ro;
        // pad slots [deg, ceil4(deg)) with zero-row index n
        int cc = min(c, CAP);
        int c4 = min((cc + 3) & ~3, CAP);
        for (int s = cc; s < c4; ++s) colx_pad[((size_t)node << 6) + s] = n;
    }
    __syncthreads();
    // fused cast: h rows of this window -> pre-scaled bf16 (16 uint4 per row)
    for (int idx = t; idx < WSZ * 16; idx += 256) {
        int rl = idx >> 4, sub = idx & 15;
        int nd = (w << 8) + rl;
        if (nd < n) {
            float s = rsO_s[rl];
            float4 a = ((const float4*)h)[(size_t)nd * 32 + sub * 2];
            float4 b = ((const float4*)h)[(size_t)nd * 32 + sub * 2 + 1];
            uint4 o;
            o.x = pack2bf(a.x * s, a.y * s);
            o.y = pack2bf(a.z * s, a.w * s);
            o.z = pack2bf(b.x * s, b.y * s);
            o.w = pack2bf(b.z * s, b.w * s);
            hb4[(size_t)nd * 16 + sub] = o;
        }
    }
}

// ---------------- SpMM gather, dwordx4: one instruction gathers 4 rows ----------------
// 16 lanes cover a 256B row; groups g=0..3 handle edges j+g. Slot list padded to 4k
// with zero-row n, so no tails. Cross-group reduce via shfl_xor; lanes g==0 write row.
__global__ __launch_bounds__(256) void spmm_bf16(const uint4* __restrict__ xb4,
                                                 const int* __restrict__ cnt_in,
                                                 const int* __restrict__ colx_pad,
                                                 const float* __restrict__ rs_in,
                                                 uint4* __restrict__ yb4, int n) {
    int node = (blockIdx.x * 256 + threadIdx.x) >> 6;
    int lane = threadIdx.x & 63;
    if (node >= n) return;
    int g = lane >> 4, sub = lane & 15;
    int cnt = min(cnt_in[node], CAP);
    int cnt4 = min((cnt + 3) & ~3, CAP);
    int myc = colx_pad[((size_t)node << 6) + ((lane < cnt4) ? lane : 0)];
    float acc[8] = {0.f, 0.f, 0.f, 0.f, 0.f, 0.f, 0.f, 0.f};
    int j = 0;
    for (; j + 16 <= cnt4; j += 16) {   // 16 edges (4 batches) in flight
        uint4 v[4];
#pragma unroll
        for (int b = 0; b < 4; ++b) {
            int c = __shfl(myc, j + 4 * b + g);
            v[b] = xb4[(size_t)c * 16 + sub];
        }
#pragma unroll
        for (int b = 0; b < 4; ++b) {
            acc[0] += __uint_as_float(v[b].x << 16);
            acc[1] += __uint_as_float(v[b].x & 0xffff0000u);
            acc[2] += __uint_as_float(v[b].y << 16);
            acc[3] += __uint_as_float(v[b].y & 0xffff0000u);
            acc[4] += __uint_as_float(v[b].z << 16);
            acc[5] += __uint_as_float(v[b].z & 0xffff0000u);
            acc[6] += __uint_as_float(v[b].w << 16);
            acc[7] += __uint_as_float(v[b].w & 0xffff0000u);
        }
    }
    for (; j < cnt4; j += 4) {
        int c = __shfl(myc, j + g);
        uint4 v = xb4[(size_t)c * 16 + sub];
        acc[0] += __uint_as_float(v.x << 16);
        acc[1] += __uint_as_float(v.x & 0xffff0000u);
        acc[2] += __uint_as_float(v.y << 16);
        acc[3] += __uint_as_float(v.y & 0xffff0000u);
        acc[4] += __uint_as_float(v.z << 16);
        acc[5] += __uint_as_float(v.z & 0xffff0000u);
        acc[6] += __uint_as_float(v.w << 16);
        acc[7] += __uint_as_float(v.w & 0xffff0000u);
    }
#pragma unroll
    for (int i = 0; i < 8; ++i) {
        acc[i] += __shfl_xor(acc[i], 16);
        acc[i] += __shfl_xor(acc[i], 32);
    }
    if (g == 0) {
        float w = rs_in[node];
        uint4 o;
        o.x = pack2bf(acc[0] * w, acc[1] * w);
        o.y = pack2bf(acc[2] * w, acc[3] * w);
        o.z = pack2bf(acc[4] * w, acc[5] * w);
        o.w = pack2bf(acc[6] * w, acc[7] * w);
        yb4[(size_t)node * 16 + sub] = o;
    }
}

// ---------------- layer-1 MM: x1b = bf16( relu(A@W1+b1) * rs_out[row] ) ----------------
// A-frag: A[m=lane&15][k0*32+q*8+j]; C/D: col=lane&15, row=q*4+reg (guide §3, m89-verified)
__global__ __launch_bounds__(256) void mm_mfma(const unsigned char* __restrict__ A,
                                               const unsigned char* __restrict__ Wt,
                                               const float* __restrict__ bias,
                                               const float* __restrict__ rs_out,
                                               unsigned short* __restrict__ out, int n) {
    int wave = threadIdx.x >> 6, lane = threadIdx.x & 63;
    int m = lane & 15, q = lane >> 4;
    int r0 = (int)blockIdx.x * 64 + wave * 16;
    int arow = min(r0 + m, n - 1);
    f4v acc[8];
#pragma unroll
    for (int c = 0; c < 8; ++c) acc[c] = (f4v){0.f, 0.f, 0.f, 0.f};
#pragma unroll
    for (int k0 = 0; k0 < 4; ++k0) {
        s8v a = *(const s8v*)(A + (size_t)arow * 256 + k0 * 64 + q * 16);
#pragma unroll
        for (int c = 0; c < 8; ++c) {
            s8v b = *(const s8v*)(Wt + (size_t)(c * 16 + m) * 256 + k0 * 64 + q * 16);
            acc[c] = __builtin_amdgcn_mfma_f32_16x16x32_bf16(a, b, acc[c], 0, 0, 0);
        }
    }
#pragma unroll
    for (int c = 0; c < 8; ++c) {
        float bv = bias[c * 16 + m];
#pragma unroll
        for (int r = 0; r < 4; ++r) {
            int row = r0 + q * 4 + r;
            if (row < n) {
                float val = fmaxf(acc[c][r] + bv, 0.0f);
                out[(size_t)row * 128 + c * 16 + m] = f2bf(val * rs_out[row]);
            }
        }
    }
}

// ---------------- layer-2 MM with FUSED mean-readout numerator ----------------
__global__ __launch_bounds__(256) void mm_mfma_readout(const unsigned char* __restrict__ A,
                                                       const unsigned char* __restrict__ Wt,
                                                       const float* __restrict__ bias,
                                                       const int* __restrict__ gid,
                                                       float* __restrict__ hg, int n) {
    __shared__ float hgloc[HL][DIM];
    int wave = threadIdx.x >> 6, lane = threadIdx.x & 63;
    int m = lane & 15, q = lane >> 4;
    int r0 = (int)blockIdx.x * 64 + wave * 16;
    int b0 = (int)blockIdx.x * 64;
    int gid0 = gid[min(b0, n - 1)];
    for (int i = threadIdx.x; i < HL * DIM; i += 256) ((float*)hgloc)[i] = 0.0f;
    __syncthreads();
    int arow = min(r0 + m, n - 1);
    f4v acc[8];
#pragma unroll
    for (int c = 0; c < 8; ++c) acc[c] = (f4v){0.f, 0.f, 0.f, 0.f};
#pragma unroll
    for (int k0 = 0; k0 < 4; ++k0) {
        s8v a = *(const s8v*)(A + (size_t)arow * 256 + k0 * 64 + q * 16);
#pragma unroll
        for (int c = 0; c < 8; ++c) {
            s8v b = *(const s8v*)(Wt + (size_t)(c * 16 + m) * 256 + k0 * 64 + q * 16);
            acc[c] = __builtin_amdgcn_mfma_f32_16x16x32_bf16(a, b, acc[c], 0, 0, 0);
        }
    }
    int gfirst = gid[min(r0, n - 1)];
    int glast = gid[min(r0 + 15, n - 1)];
    bool uni = (gfirst == glast) && (r0 + 15 < n);
    if (uni) {
        int gl = gfirst - gid0;
#pragma unroll
        for (int c = 0; c < 8; ++c) {
            float bv = bias[c * 16 + m];
            float s = fmaxf(acc[c][0] + bv, 0.0f) + fmaxf(acc[c][1] + bv, 0.0f) +
                      fmaxf(acc[c][2] + bv, 0.0f) + fmaxf(acc[c][3] + bv, 0.0f);
            s += __shfl_xor(s, 16);
            s += __shfl_xor(s, 32);
            if (q == 0) {
                if (gl < HL)
                    atomicAdd(&hgloc[gl][c * 16 + m], s);
                else
                    atomicAdd(&hg[(size_t)gfirst * DIM + c * 16 + m], s);
            }
        }
    } else {
#pragma unroll
        for (int r = 0; r < 4; ++r) {
            int row = r0 + q * 4 + r;
            if (row < n) {
                int g = gid[row];
                int gl = g - gid0;
#pragma unroll
                for (int c = 0; c < 8; ++c) {
                    float val = fmaxf(acc[c][r] + bias[c * 16 + m], 0.0f);
                    if (gl < HL)
                        atomicAdd(&hgloc[gl][c * 16 + m], val);
                    else
                        atomicAdd(&hg[(size_t)g * DIM + c * 16 + m], val);
                }
            }
        }
    }
    __syncthreads();
    for (int i = threadIdx.x; i < HL * DIM; i += 256) {
        float v = ((float*)hgloc)[i];
        int g = gid0 + (i >> 7);
        if (v != 0.0f && g < NG) atomicAdd(&hg[(size_t)g * DIM + (i & 127)], v);
    }
}

// ---------------- classifier: one block per graph, fused count ----------------
__global__ void classify_kernel(const float* __restrict__ hg, const int* __restrict__ gid,
                                const float* __restrict__ Wc, const float* __restrict__ bc,
                                float* __restrict__ out, int n) {
    __shared__ float inv;
    int g = blockIdx.x, t = threadIdx.x;
    if (t == 0) {
        int lo = 0, hi = n;
        while (lo < hi) { int mid = (lo + hi) >> 1; if (gid[mid] < g) lo = mid + 1; else hi = mid; }
        int lb = lo;
        lo = 0; hi = n;
        while (lo < hi) { int mid = (lo + hi) >> 1; if (gid[mid] <= g) lo = mid + 1; else hi = mid; }
        inv = 1.0f / fmaxf((float)(lo - lb), 1.0f);
    }
    __syncthreads();
    if (t < NCLS) {
        float s = 0.0f;
        for (int k = 0; k < DIM; ++k) s = fmaf(hg[g * DIM + k], Wc[k * NCLS + t], s);
        out[g * NCLS + t] = s * inv + bc[t];
    }
}

extern "C" void kernel_launch(void* const* d_in, const int* in_sizes, int n_in,
                              void* d_out, int out_size, void* d_ws, size_t ws_size,
                              hipStream_t stream) {
    const float* h   = (const float*)d_in[0];
    const int*   src = (const int*)d_in[1];
    const int*   dst = (const int*)d_in[2];
    const int*   gid = (const int*)d_in[3];
    const float* W1  = (const float*)d_in[4];
    const float* b1  = (const float*)d_in[5];
    const float* W2  = (const float*)d_in[6];
    const float* b2  = (const float*)d_in[7];
    const float* Wc  = (const float*)d_in[8];
    const float* bc  = (const float*)d_in[9];
    float* out = (float*)d_out;

    const int n = in_sizes[0] / DIM;   // 100000
    const int e = in_sizes[1];         // 1600000
    const int nw = (n + WSZ - 1) / WSZ;   // 391 windows

    // workspace layout (256B aligned)
    char* ws = (char*)d_ws;
    size_t off = 0;
    auto alloc = [&](size_t bytes) -> char* {
        char* p = ws + off;
        off = (off + bytes + 255) & ~(size_t)255;
        return p;
    };
    int*   cnt_in  = (int*)alloc((size_t)n * 4);
    float* rs_in   = (float*)alloc((size_t)n * 4);
    float* rs_out  = (float*)alloc((size_t)n * 4);
    int*   curD    = (int*)alloc((size_t)NWMAX * 4);
    int*   curS    = (int*)alloc((size_t)NWMAX * 4);
    int*   colx_pad = (int*)alloc((size_t)n * CAP * 4);          // 25.6 MB
    int*   bucketD = (int*)alloc((size_t)nw * CAPB * 4);         // 12.8 MB
    unsigned char* bucketS = (unsigned char*)alloc((size_t)nw * CAPB);  // 3.2 MB
    float* hg      = (float*)alloc((size_t)NG * DIM * 4);
    unsigned short* Wt1 = (unsigned short*)alloc(128 * 128 * 2);
    unsigned short* Wt2 = (unsigned short*)alloc(128 * 128 * 2);
    // feature tables have n+1 rows (row n = zeros, gather-padding target)
    uint4* hb4  = (uint4*)alloc((size_t)(n + 4) * 64 * 4);
    uint4* aggB = (uint4*)alloc((size_t)(n + 4) * 64 * 4);
    uint4* x1b4 = (uint4*)alloc((size_t)(n + 4) * 64 * 4);

    const int SPMM_B = (n + 3) / 4;
    const int MM_B = (n + 63) / 64;
    const int AB = (e + EPB - 1) / EPB;

    (void)hipMemsetAsync(hg, 0, (size_t)NG * DIM * 4, stream);

    prep_kernel<<<128, 256, 0, stream>>>(W1, W2, Wt1, Wt2, curD, curS, hb4, x1b4, nw, n);
    bucket_kernel<<<AB, 256, 0, stream>>>(src, dst, curD, curS, bucketD, bucketS, e, nw);
    window_kernel<<<nw, 256, 0, stream>>>(curD, curS, bucketD, bucketS, h,
                                          cnt_in, rs_in, rs_out, colx_pad, hb4, n);

    // layer 1
    spmm_bf16<<<SPMM_B, 256, 0, stream>>>(hb4, cnt_in, colx_pad, rs_in, aggB, n);
    mm_mfma<<<MM_B, 256, 0, stream>>>((const unsigned char*)aggB,
                                      (const unsigned char*)Wt1, b1, rs_out,
                                      (unsigned short*)x1b4, n);
    // layer 2 + fused readout numerator
    spmm_bf16<<<SPMM_B, 256, 0, stream>>>(x1b4, cnt_in, colx_pad, rs_in, aggB, n);
    mm_mfma_readout<<<MM_B, 256, 0, stream>>>((const unsigned char*)aggB,
                                              (const unsigned char*)Wt2, b2, gid, hg, n);
    // classify (fused per-graph count)
    classify_kernel<<<NG, 64, 0, stream>>>(hg, gid, Wc, bc, out, n);
}

// Round 10
// 324.090 us; speedup vs baseline: 1.5553x; 1.1204x over previous
//
#include <hip/hip_runtime.h>

#define DIM 128
#define NG 64
#define NCLS 10
#define CAP 64             // padded-CSR slots per node; P(deg>=64 | lambda=16) ~ 2e-13
#define WSZ 256            // nodes per window (dst/src bucketing granularity)
#define NWMAX 512          // max windows (n <= 131072)
#define CAPB 8192          // edges per window bucket (mean 4096, +64 sigma)
#define EPB 8192           // edges per bucket_kernel block
#define HL 4               // local readout accumulator graphs per block
#define WTP 68             // LDS Wt row stride in words (272 B: 16-row frag reads -> 2-way bank alias = free)

typedef __attribute__((ext_vector_type(8))) short s8v;
typedef __attribute__((ext_vector_type(4))) float f4v;

__device__ inline unsigned short f2bf(float f) {
    unsigned int u = __float_as_uint(f);
    unsigned int r = (u + 0x7fffu + ((u >> 16) & 1u)) >> 16;
    return (unsigned short)r;
}
__device__ inline unsigned int pack2bf(float a, float b) {
    return ((unsigned int)f2bf(b) << 16) | (unsigned int)f2bf(a);
}

// ---------------- prep: cursors + weight cast/transpose + zero rows ----------------
__global__ void prep_kernel(const float* __restrict__ W1, const float* __restrict__ W2,
                            unsigned short* __restrict__ Wt1, unsigned short* __restrict__ Wt2,
                            int* curD, int* curS, uint4* hb4, uint4* x1b4, int nw, int n) {
    int t = blockIdx.x * 256 + threadIdx.x;
    if (t < nw) {
        curD[t] = t * CAPB;
        curS[t] = t * CAPB;
    }
    if (t < 32768) {
        int which = t >> 14;
        int i = t & 16383;
        int c = i >> 7, k = i & 127;
        (which ? Wt2 : Wt1)[i] = f2bf((which ? W2 : W1)[k * 128 + c]);
    }
    if (t < 16) {   // zero row at index n (gather padding target)
        uint4 z = make_uint4(0, 0, 0, 0);
        hb4[(size_t)n * 16 + t] = z;
        x1b4[(size_t)n * 16 + t] = z;
    }
}

// ---------------- Phase A: bucket edges by dst>>8 (packed) and src>>8 (byte) ----------------
__global__ __launch_bounds__(256) void bucket_kernel(const int* __restrict__ src,
                                                     const int* __restrict__ dst,
                                                     int* curD, int* curS,
                                                     int* __restrict__ bucketD,
                                                     unsigned char* __restrict__ bucketS,
                                                     int e, int nw) {
    __shared__ int histD[NWMAX];
    __shared__ int histS[NWMAX];
    int t = threadIdx.x;
    for (int i = t; i < nw; i += 256) { histD[i] = 0; histS[i] = 0; }
    __syncthreads();
    int lo = blockIdx.x * EPB;
    int hi = min(e, lo + EPB);
    for (int i = lo + t * 4; i < hi; i += 1024) {
        int4 d4 = *(const int4*)&dst[i];
        int4 s4 = *(const int4*)&src[i];
        atomicAdd(&histD[d4.x >> 8], 1); atomicAdd(&histS[s4.x >> 8], 1);
        atomicAdd(&histD[d4.y >> 8], 1); atomicAdd(&histS[s4.y >> 8], 1);
        atomicAdd(&histD[d4.z >> 8], 1); atomicAdd(&histS[s4.z >> 8], 1);
        atomicAdd(&histD[d4.w >> 8], 1); atomicAdd(&histS[s4.w >> 8], 1);
    }
    __syncthreads();
    for (int i = t; i < nw; i += 256) {
        int hd = histD[i], hs = histS[i];
        histD[i] = hd ? atomicAdd(&curD[i], hd) : 0;
        histS[i] = hs ? atomicAdd(&curS[i], hs) : 0;
    }
    __syncthreads();
    for (int i = lo + t * 4; i < hi; i += 1024) {
        int4 d4 = *(const int4*)&dst[i];
        int4 s4 = *(const int4*)&src[i];
#pragma unroll
        for (int j = 0; j < 4; ++j) {
            int d = (&d4.x)[j], s = (&s4.x)[j];
            int sd = atomicAdd(&histD[d >> 8], 1);
            bucketD[sd] = (s << 8) | (d & 255);
            int ss = atomicAdd(&histS[s >> 8], 1);
            bucketS[ss] = (unsigned char)(s & 255);
        }
    }
}

// ---------------- Phase B: window CSR fill + degrees + rs + FUSED h cast ----------------
__global__ __launch_bounds__(256) void window_kernel(const int* __restrict__ curD,
                                                     const int* __restrict__ curS,
                                                     const int* __restrict__ bucketD,
                                                     const unsigned char* __restrict__ bucketS,
                                                     const float* __restrict__ h,
                                                     int* __restrict__ cnt_in,
                                                     float* __restrict__ rs_in,
                                                     float* __restrict__ rs_out,
                                                     int* __restrict__ colx_pad,
                                                     uint4* __restrict__ hb4, int n) {
    __shared__ int cin[WSZ];
    __shared__ int cout[WSZ];
    __shared__ float rsO_s[WSZ];
    int w = blockIdx.x, t = threadIdx.x;
    cin[t] = 0;
    cout[t] = 0;
    __syncthreads();
    int base = w * CAPB;
    int nE = min(curD[w] - base, CAPB);
    for (int i = t; i < nE; i += 256) {
        int v = bucketD[base + i];
        int d8 = v & 255;
        int slot = atomicAdd(&cin[d8], 1);
        if (slot < CAP) colx_pad[(((w << 8) + d8) << 6) + slot] = v >> 8;
    }
    int nS = min(curS[w] - base, CAPB);
    for (int i = t; i < nS; i += 256) atomicAdd(&cout[bucketS[base + i]], 1);
    __syncthreads();
    int node = (w << 8) + t;
    if (node < n) {
        int c = cin[t];
        cnt_in[node] = c;
        rs_in[node] = rsqrtf(fmaxf((float)c, 1.0f));
        float ro = rsqrtf(fmaxf((float)cout[t], 1.0f));
        rs_out[node] = ro;
        rsO_s[t] = ro;
        int cc = min(c, CAP);
        int c4 = min((cc + 3) & ~3, CAP);
        for (int s = cc; s < c4; ++s) colx_pad[((size_t)node << 6) + s] = n;
    }
    __syncthreads();
    for (int idx = t; idx < WSZ * 16; idx += 256) {
        int rl = idx >> 4, sub = idx & 15;
        int nd = (w << 8) + rl;
        if (nd < n) {
            float s = rsO_s[rl];
            float4 a = ((const float4*)h)[(size_t)nd * 32 + sub * 2];
            float4 b = ((const float4*)h)[(size_t)nd * 32 + sub * 2 + 1];
            uint4 o;
            o.x = pack2bf(a.x * s, a.y * s);
            o.y = pack2bf(a.z * s, a.w * s);
            o.z = pack2bf(b.x * s, b.y * s);
            o.w = pack2bf(b.z * s, b.w * s);
            hb4[(size_t)nd * 16 + sub] = o;
        }
    }
}

// ---------------- SpMM gather, dwordx4: one instruction gathers 4 rows ----------------
__global__ __launch_bounds__(256) void spmm_bf16(const uint4* __restrict__ xb4,
                                                 const int* __restrict__ cnt_in,
                                                 const int* __restrict__ colx_pad,
                                                 const float* __restrict__ rs_in,
                                                 uint4* __restrict__ yb4, int n) {
    int node = (blockIdx.x * 256 + threadIdx.x) >> 6;
    int lane = threadIdx.x & 63;
    if (node >= n) return;
    int g = lane >> 4, sub = lane & 15;
    int cnt = min(cnt_in[node], CAP);
    int cnt4 = min((cnt + 3) & ~3, CAP);
    int myc = colx_pad[((size_t)node << 6) + ((lane < cnt4) ? lane : 0)];
    float acc[8] = {0.f, 0.f, 0.f, 0.f, 0.f, 0.f, 0.f, 0.f};
    int j = 0;
    for (; j + 16 <= cnt4; j += 16) {
        uint4 v[4];
#pragma unroll
        for (int b = 0; b < 4; ++b) {
            int c = __shfl(myc, j + 4 * b + g);
            v[b] = xb4[(size_t)c * 16 + sub];
        }
#pragma unroll
        for (int b = 0; b < 4; ++b) {
            acc[0] += __uint_as_float(v[b].x << 16);
            acc[1] += __uint_as_float(v[b].x & 0xffff0000u);
            acc[2] += __uint_as_float(v[b].y << 16);
            acc[3] += __uint_as_float(v[b].y & 0xffff0000u);
            acc[4] += __uint_as_float(v[b].z << 16);
            acc[5] += __uint_as_float(v[b].z & 0xffff0000u);
            acc[6] += __uint_as_float(v[b].w << 16);
            acc[7] += __uint_as_float(v[b].w & 0xffff0000u);
        }
    }
    for (; j < cnt4; j += 4) {
        int c = __shfl(myc, j + g);
        uint4 v = xb4[(size_t)c * 16 + sub];
        acc[0] += __uint_as_float(v.x << 16);
        acc[1] += __uint_as_float(v.x & 0xffff0000u);
        acc[2] += __uint_as_float(v.y << 16);
        acc[3] += __uint_as_float(v.y & 0xffff0000u);
        acc[4] += __uint_as_float(v.z << 16);
        acc[5] += __uint_as_float(v.z & 0xffff0000u);
        acc[6] += __uint_as_float(v.w << 16);
        acc[7] += __uint_as_float(v.w & 0xffff0000u);
    }
#pragma unroll
    for (int i = 0; i < 8; ++i) {
        acc[i] += __shfl_xor(acc[i], 16);
        acc[i] += __shfl_xor(acc[i], 32);
    }
    if (g == 0) {
        float w = rs_in[node];
        uint4 o;
        o.x = pack2bf(acc[0] * w, acc[1] * w);
        o.y = pack2bf(acc[2] * w, acc[3] * w);
        o.z = pack2bf(acc[4] * w, acc[5] * w);
        o.w = pack2bf(acc[6] * w, acc[7] * w);
        yb4[(size_t)node * 16 + sub] = o;
    }
}

// ---------------- stage Wt (32KB) into LDS with padded stride ----------------
// Global row stride 256B -> LDS 272B. B-frag ds_read_b128 at (c*16+m)*272 + k0*64 + q*16:
// 16 m-lanes stride 272B = 68 words = 4 mod 32 -> 2 lanes/bank (free) vs 16-way at 256B.
__device__ inline void stage_wt(const uint4* __restrict__ Wt4, unsigned int* WtL, int t) {
#pragma unroll
    for (int i = 0; i < 8; ++i) {
        int q = t + 256 * i;           // 0..2047
        int row = q >> 4, col4 = q & 15;
        *(uint4*)&WtL[row * WTP + col4 * 4] = Wt4[q];
    }
}

// ---------------- layer-1 MM: x1b = bf16( relu(A@W1+b1) * rs_out[row] ) ----------------
// B-frags from LDS (fixes the 58us B-load latency chain: compiler pipelines ds_read/lgkmcnt).
// A-frag: A[m=lane&15][k0*32+q*8+j]; C/D: col=lane&15, row=q*4+reg (guide §3, m89-verified)
__global__ __launch_bounds__(256) void mm_mfma(const unsigned char* __restrict__ A,
                                               const uint4* __restrict__ Wt4,
                                               const float* __restrict__ bias,
                                               const float* __restrict__ rs_out,
                                               unsigned short* __restrict__ out, int n) {
    __shared__ unsigned int WtL[128 * WTP];   // 34.8 KB
    int t = threadIdx.x;
    stage_wt(Wt4, WtL, t);
    int wave = t >> 6, lane = t & 63;
    int m = lane & 15, q = lane >> 4;
    int r0 = (int)blockIdx.x * 64 + wave * 16;
    int arow = min(r0 + m, n - 1);
    __syncthreads();
    f4v acc[8];
#pragma unroll
    for (int c = 0; c < 8; ++c) acc[c] = (f4v){0.f, 0.f, 0.f, 0.f};
#pragma unroll
    for (int k0 = 0; k0 < 4; ++k0) {
        s8v a = *(const s8v*)(A + (size_t)arow * 256 + k0 * 64 + q * 16);
#pragma unroll
        for (int c = 0; c < 8; ++c) {
            s8v b = *(const s8v*)&WtL[(c * 16 + m) * WTP + k0 * 16 + q * 4];
            acc[c] = __builtin_amdgcn_mfma_f32_16x16x32_bf16(a, b, acc[c], 0, 0, 0);
        }
    }
#pragma unroll
    for (int c = 0; c < 8; ++c) {
        float bv = bias[c * 16 + m];
#pragma unroll
        for (int r = 0; r < 4; ++r) {
            int row = r0 + q * 4 + r;
            if (row < n) {
                float val = fmaxf(acc[c][r] + bv, 0.0f);
                out[(size_t)row * 128 + c * 16 + m] = f2bf(val * rs_out[row]);
            }
        }
    }
}

// ---------------- layer-2 MM with FUSED mean-readout numerator (LDS Wt too) ----------------
__global__ __launch_bounds__(256) void mm_mfma_readout(const unsigned char* __restrict__ A,
                                                       const uint4* __restrict__ Wt4,
                                                       const float* __restrict__ bias,
                                                       const int* __restrict__ gid,
                                                       float* __restrict__ hg, int n) {
    __shared__ unsigned int WtL[128 * WTP];   // 34.8 KB
    __shared__ float hgloc[HL][DIM];          // 2 KB
    int t = threadIdx.x;
    stage_wt(Wt4, WtL, t);
    for (int i = t; i < HL * DIM; i += 256) ((float*)hgloc)[i] = 0.0f;
    int wave = t >> 6, lane = t & 63;
    int m = lane & 15, q = lane >> 4;
    int r0 = (int)blockIdx.x * 64 + wave * 16;
    int b0 = (int)blockIdx.x * 64;
    int gid0 = gid[min(b0, n - 1)];
    int arow = min(r0 + m, n - 1);
    __syncthreads();
    f4v acc[8];
#pragma unroll
    for (int c = 0; c < 8; ++c) acc[c] = (f4v){0.f, 0.f, 0.f, 0.f};
#pragma unroll
    for (int k0 = 0; k0 < 4; ++k0) {
        s8v a = *(const s8v*)(A + (size_t)arow * 256 + k0 * 64 + q * 16);
#pragma unroll
        for (int c = 0; c < 8; ++c) {
            s8v b = *(const s8v*)&WtL[(c * 16 + m) * WTP + k0 * 16 + q * 4];
            acc[c] = __builtin_amdgcn_mfma_f32_16x16x32_bf16(a, b, acc[c], 0, 0, 0);
        }
    }
    int gfirst = gid[min(r0, n - 1)];
    int glast = gid[min(r0 + 15, n - 1)];
    bool uni = (gfirst == glast) && (r0 + 15 < n);
    if (uni) {
        int gl = gfirst - gid0;
#pragma unroll
        for (int c = 0; c < 8; ++c) {
            float bv = bias[c * 16 + m];
            float s = fmaxf(acc[c][0] + bv, 0.0f) + fmaxf(acc[c][1] + bv, 0.0f) +
                      fmaxf(acc[c][2] + bv, 0.0f) + fmaxf(acc[c][3] + bv, 0.0f);
            s += __shfl_xor(s, 16);
            s += __shfl_xor(s, 32);
            if (q == 0) {
                if (gl < HL)
                    atomicAdd(&hgloc[gl][c * 16 + m], s);
                else
                    atomicAdd(&hg[(size_t)gfirst * DIM + c * 16 + m], s);
            }
        }
    } else {
#pragma unroll
        for (int r = 0; r < 4; ++r) {
            int row = r0 + q * 4 + r;
            if (row < n) {
                int g = gid[row];
                int gl = g - gid0;
#pragma unroll
                for (int c = 0; c < 8; ++c) {
                    float val = fmaxf(acc[c][r] + bias[c * 16 + m], 0.0f);
                    if (gl < HL)
                        atomicAdd(&hgloc[gl][c * 16 + m], val);
                    else
                        atomicAdd(&hg[(size_t)g * DIM + c * 16 + m], val);
                }
            }
        }
    }
    __syncthreads();
    for (int i = t; i < HL * DIM; i += 256) {
        float v = ((float*)hgloc)[i];
        int g = gid0 + (i >> 7);
        if (v != 0.0f && g < NG) atomicAdd(&hg[(size_t)g * DIM + (i & 127)], v);
    }
}

// ---------------- classifier: one block per graph, fused count ----------------
__global__ void classify_kernel(const float* __restrict__ hg, const int* __restrict__ gid,
                                const float* __restrict__ Wc, const float* __restrict__ bc,
                                float* __restrict__ out, int n) {
    __shared__ float inv;
    int g = blockIdx.x, t = threadIdx.x;
    if (t == 0) {
        int lo = 0, hi = n;
        while (lo < hi) { int mid = (lo + hi) >> 1; if (gid[mid] < g) lo = mid + 1; else hi = mid; }
        int lb = lo;
        lo = 0; hi = n;
        while (lo < hi) { int mid = (lo + hi) >> 1; if (gid[mid] <= g) lo = mid + 1; else hi = mid; }
        inv = 1.0f / fmaxf((float)(lo - lb), 1.0f);
    }
    __syncthreads();
    if (t < NCLS) {
        float s = 0.0f;
        for (int k = 0; k < DIM; ++k) s = fmaf(hg[g * DIM + k], Wc[k * NCLS + t], s);
        out[g * NCLS + t] = s * inv + bc[t];
    }
}

extern "C" void kernel_launch(void* const* d_in, const int* in_sizes, int n_in,
                              void* d_out, int out_size, void* d_ws, size_t ws_size,
                              hipStream_t stream) {
    const float* h   = (const float*)d_in[0];
    const int*   src = (const int*)d_in[1];
    const int*   dst = (const int*)d_in[2];
    const int*   gid = (const int*)d_in[3];
    const float* W1  = (const float*)d_in[4];
    const float* b1  = (const float*)d_in[5];
    const float* W2  = (const float*)d_in[6];
    const float* b2  = (const float*)d_in[7];
    const float* Wc  = (const float*)d_in[8];
    const float* bc  = (const float*)d_in[9];
    float* out = (float*)d_out;

    const int n = in_sizes[0] / DIM;   // 100000
    const int e = in_sizes[1];         // 1600000
    const int nw = (n + WSZ - 1) / WSZ;   // 391 windows

    char* ws = (char*)d_ws;
    size_t off = 0;
    auto alloc = [&](size_t bytes) -> char* {
        char* p = ws + off;
        off = (off + bytes + 255) & ~(size_t)255;
        return p;
    };
    int*   cnt_in  = (int*)alloc((size_t)n * 4);
    float* rs_in   = (float*)alloc((size_t)n * 4);
    float* rs_out  = (float*)alloc((size_t)n * 4);
    int*   curD    = (int*)alloc((size_t)NWMAX * 4);
    int*   curS    = (int*)alloc((size_t)NWMAX * 4);
    int*   colx_pad = (int*)alloc((size_t)n * CAP * 4);          // 25.6 MB
    int*   bucketD = (int*)alloc((size_t)nw * CAPB * 4);         // 12.8 MB
    unsigned char* bucketS = (unsigned char*)alloc((size_t)nw * CAPB);  // 3.2 MB
    float* hg      = (float*)alloc((size_t)NG * DIM * 4);
    unsigned short* Wt1 = (unsigned short*)alloc(128 * 128 * 2);
    unsigned short* Wt2 = (unsigned short*)alloc(128 * 128 * 2);
    uint4* hb4  = (uint4*)alloc((size_t)(n + 4) * 64 * 4);
    uint4* aggB = (uint4*)alloc((size_t)(n + 4) * 64 * 4);
    uint4* x1b4 = (uint4*)alloc((size_t)(n + 4) * 64 * 4);

    const int SPMM_B = (n + 3) / 4;
    const int MM_B = (n + 63) / 64;
    const int AB = (e + EPB - 1) / EPB;

    (void)hipMemsetAsync(hg, 0, (size_t)NG * DIM * 4, stream);

    prep_kernel<<<128, 256, 0, stream>>>(W1, W2, Wt1, Wt2, curD, curS, hb4, x1b4, nw, n);
    bucket_kernel<<<AB, 256, 0, stream>>>(src, dst, curD, curS, bucketD, bucketS, e, nw);
    window_kernel<<<nw, 256, 0, stream>>>(curD, curS, bucketD, bucketS, h,
                                          cnt_in, rs_in, rs_out, colx_pad, hb4, n);

    // layer 1
    spmm_bf16<<<SPMM_B, 256, 0, stream>>>(hb4, cnt_in, colx_pad, rs_in, aggB, n);
    mm_mfma<<<MM_B, 256, 0, stream>>>((const unsigned char*)aggB, (const uint4*)Wt1,
                                      b1, rs_out, (unsigned short*)x1b4, n);
    // layer 2 + fused readout numerator
    spmm_bf16<<<SPMM_B, 256, 0, stream>>>(x1b4, cnt_in, colx_pad, rs_in, aggB, n);
    mm_mfma_readout<<<MM_B, 256, 0, stream>>>((const unsigned char*)aggB, (const uint4*)Wt2,
                                              b2, gid, hg, n);
    // classify (fused per-graph count)
    classify_kernel<<<NG, 64, 0, stream>>>(hg, gid, Wc, bc, out, n);
}

// Round 11
// 309.360 us; speedup vs baseline: 1.6293x; 1.0476x over previous
//
#include <hip/hip_runtime.h>

#define DIM 128
#define NG 64
#define NCLS 10
#define CAP 64             // padded-CSR slots per node; P(deg>=64 | lambda=16) ~ 2e-13
#define WSZ 256            // nodes per window (dst/src bucketing granularity)
#define NWMAX 512          // max windows (n <= 131072)
#define CAPB 8192          // edges per window bucket (mean 4096, +64 sigma)
#define EPB 8192           // edges per bucket_kernel block
#define HL 4               // local readout accumulator graphs per block
#define WTP 68             // LDS Wt row stride in words (272 B: frag reads 2-way bank alias = free)

typedef __attribute__((ext_vector_type(8))) short s8v;
typedef __attribute__((ext_vector_type(4))) float f4v;

__device__ inline unsigned short f2bf(float f) {
    unsigned int u = __float_as_uint(f);
    unsigned int r = (u + 0x7fffu + ((u >> 16) & 1u)) >> 16;
    return (unsigned short)r;
}
__device__ inline unsigned int pack2bf(float a, float b) {
    return ((unsigned int)f2bf(b) << 16) | (unsigned int)f2bf(a);
}

// ---------------- prep: cursors + weight cast/transpose + zero rows + hg zero ----------------
__global__ void prep_kernel(const float* __restrict__ W1, const float* __restrict__ W2,
                            unsigned short* __restrict__ Wt1, unsigned short* __restrict__ Wt2,
                            int* curD, int* curS, uint4* hb4, uint4* x1b4,
                            float* __restrict__ hg, int nw, int n) {
    int t = blockIdx.x * 256 + threadIdx.x;
    if (t < nw) {
        curD[t] = t * CAPB;
        curS[t] = t * CAPB;
    }
    if (t < 32768) {
        int which = t >> 14;
        int i = t & 16383;
        int c = i >> 7, k = i & 127;
        (which ? Wt2 : Wt1)[i] = f2bf((which ? W2 : W1)[k * 128 + c]);
    }
    if (t < NG * DIM) hg[t] = 0.0f;   // replaces hipMemsetAsync
    if (t < 16) {   // zero row at index n (gather padding target)
        uint4 z = make_uint4(0, 0, 0, 0);
        hb4[(size_t)n * 16 + t] = z;
        x1b4[(size_t)n * 16 + t] = z;
    }
}

// ---------------- Phase A: bucket edges; 1024 threads (16 waves) for latency hiding ----------
// Only ~196 blocks -> <=1 block/CU; at 256 threads that was 4 waves/CU on an LDS-atomic
// latency chain. 16 waves/CU hides it. Per-edge path still uses ONLY LDS atomics.
__global__ __launch_bounds__(1024) void bucket_kernel(const int* __restrict__ src,
                                                      const int* __restrict__ dst,
                                                      int* curD, int* curS,
                                                      int* __restrict__ bucketD,
                                                      unsigned char* __restrict__ bucketS,
                                                      int e, int nw) {
    __shared__ int histD[NWMAX];
    __shared__ int histS[NWMAX];
    int t = threadIdx.x;
    for (int i = t; i < nw; i += 1024) { histD[i] = 0; histS[i] = 0; }
    __syncthreads();
    int lo = blockIdx.x * EPB;
    int hi = min(e, lo + EPB);
    for (int i = lo + t * 4; i < hi; i += 4096) {
        int4 d4 = *(const int4*)&dst[i];
        int4 s4 = *(const int4*)&src[i];
        atomicAdd(&histD[d4.x >> 8], 1); atomicAdd(&histS[s4.x >> 8], 1);
        atomicAdd(&histD[d4.y >> 8], 1); atomicAdd(&histS[s4.y >> 8], 1);
        atomicAdd(&histD[d4.z >> 8], 1); atomicAdd(&histS[s4.z >> 8], 1);
        atomicAdd(&histD[d4.w >> 8], 1); atomicAdd(&histS[s4.w >> 8], 1);
    }
    __syncthreads();
    for (int i = t; i < nw; i += 1024) {
        int hd = histD[i], hs = histS[i];
        histD[i] = hd ? atomicAdd(&curD[i], hd) : 0;
        histS[i] = hs ? atomicAdd(&curS[i], hs) : 0;
    }
    __syncthreads();
    for (int i = lo + t * 4; i < hi; i += 4096) {
        int4 d4 = *(const int4*)&dst[i];
        int4 s4 = *(const int4*)&src[i];
#pragma unroll
        for (int j = 0; j < 4; ++j) {
            int d = (&d4.x)[j], s = (&s4.x)[j];
            int sd = atomicAdd(&histD[d >> 8], 1);
            bucketD[sd] = (s << 8) | (d & 255);
            int ss = atomicAdd(&histS[s >> 8], 1);
            bucketS[ss] = (unsigned char)(s & 255);
        }
    }
}

// ---------------- Phase B: window CSR fill + degrees + rs + FUSED h cast; 512 threads ---------
// Slot lists padded to a multiple of 8 with zero-row n (spmm tail = one 2-batch group).
__global__ __launch_bounds__(512) void window_kernel(const int* __restrict__ curD,
                                                     const int* __restrict__ curS,
                                                     const int* __restrict__ bucketD,
                                                     const unsigned char* __restrict__ bucketS,
                                                     const float* __restrict__ h,
                                                     int* __restrict__ cnt_in,
                                                     float* __restrict__ rs_in,
                                                     float* __restrict__ rs_out,
                                                     int* __restrict__ colx_pad,
                                                     uint4* __restrict__ hb4, int n) {
    __shared__ int cin[WSZ];
    __shared__ int cout[WSZ];
    __shared__ float rsO_s[WSZ];
    int w = blockIdx.x, t = threadIdx.x;
    if (t < WSZ) { cin[t] = 0; cout[t] = 0; }
    __syncthreads();
    int base = w * CAPB;
    int nE = min(curD[w] - base, CAPB);
    for (int i = t; i < nE; i += 512) {
        int v = bucketD[base + i];
        int d8 = v & 255;
        int slot = atomicAdd(&cin[d8], 1);
        if (slot < CAP) colx_pad[(((w << 8) + d8) << 6) + slot] = v >> 8;
    }
    int nS = min(curS[w] - base, CAPB);
    for (int i = t; i < nS; i += 512) atomicAdd(&cout[bucketS[base + i]], 1);
    __syncthreads();
    if (t < WSZ) {
        int node = (w << 8) + t;
        if (node < n) {
            int c = cin[t];
            cnt_in[node] = c;
            rs_in[node] = rsqrtf(fmaxf((float)c, 1.0f));
            float ro = rsqrtf(fmaxf((float)cout[t], 1.0f));
            rs_out[node] = ro;
            rsO_s[t] = ro;
            int cc = min(c, CAP);
            int c8 = min((cc + 7) & ~7, CAP);   // pad to multiple of 8
            for (int s = cc; s < c8; ++s) colx_pad[((size_t)node << 6) + s] = n;
        }
    }
    __syncthreads();
    for (int idx = t; idx < WSZ * 16; idx += 512) {
        int rl = idx >> 4, sub = idx & 15;
        int nd = (w << 8) + rl;
        if (nd < n) {
            float s = rsO_s[rl];
            float4 a = ((const float4*)h)[(size_t)nd * 32 + sub * 2];
            float4 b = ((const float4*)h)[(size_t)nd * 32 + sub * 2 + 1];
            uint4 o;
            o.x = pack2bf(a.x * s, a.y * s);
            o.y = pack2bf(a.z * s, a.w * s);
            o.z = pack2bf(b.x * s, b.y * s);
            o.w = pack2bf(b.z * s, b.w * s);
            hb4[(size_t)nd * 16 + sub] = o;
        }
    }
}

// ---------------- SpMM gather, dwordx4, pad-8 slots: tail = one 2-batch group ----------------
__global__ __launch_bounds__(256) void spmm_bf16(const uint4* __restrict__ xb4,
                                                 const int* __restrict__ cnt_in,
                                                 const int* __restrict__ colx_pad,
                                                 const float* __restrict__ rs_in,
                                                 uint4* __restrict__ yb4, int n) {
    int node = (blockIdx.x * 256 + threadIdx.x) >> 6;
    int lane = threadIdx.x & 63;
    if (node >= n) return;
    int g = lane >> 4, sub = lane & 15;
    int cnt = min(cnt_in[node], CAP);
    int cnt8 = min((cnt + 7) & ~7, CAP);
    int myc = colx_pad[((size_t)node << 6) + ((lane < cnt8) ? lane : 0)];
    float acc[8] = {0.f, 0.f, 0.f, 0.f, 0.f, 0.f, 0.f, 0.f};
    int j = 0;
    for (; j + 16 <= cnt8; j += 16) {   // 16 edges, 4 batches in flight
        uint4 v[4];
#pragma unroll
        for (int b = 0; b < 4; ++b) {
            int c = __shfl(myc, j + 4 * b + g);
            v[b] = xb4[(size_t)c * 16 + sub];
        }
#pragma unroll
        for (int b = 0; b < 4; ++b) {
            acc[0] += __uint_as_float(v[b].x << 16);
            acc[1] += __uint_as_float(v[b].x & 0xffff0000u);
            acc[2] += __uint_as_float(v[b].y << 16);
            acc[3] += __uint_as_float(v[b].y & 0xffff0000u);
            acc[4] += __uint_as_float(v[b].z << 16);
            acc[5] += __uint_as_float(v[b].z & 0xffff0000u);
            acc[6] += __uint_as_float(v[b].w << 16);
            acc[7] += __uint_as_float(v[b].w & 0xffff0000u);
        }
    }
    if (j < cnt8) {   // exactly 8 edges: 2 batches, loads issued together
        int c0 = __shfl(myc, j + g);
        int c1 = __shfl(myc, j + 4 + g);
        uint4 v0 = xb4[(size_t)c0 * 16 + sub];
        uint4 v1 = xb4[(size_t)c1 * 16 + sub];
#pragma unroll
        for (int b = 0; b < 2; ++b) {
            uint4 v = b ? v1 : v0;
            acc[0] += __uint_as_float(v.x << 16);
            acc[1] += __uint_as_float(v.x & 0xffff0000u);
            acc[2] += __uint_as_float(v.y << 16);
            acc[3] += __uint_as_float(v.y & 0xffff0000u);
            acc[4] += __uint_as_float(v.z << 16);
            acc[5] += __uint_as_float(v.z & 0xffff0000u);
            acc[6] += __uint_as_float(v.w << 16);
            acc[7] += __uint_as_float(v.w & 0xffff0000u);
        }
    }
#pragma unroll
    for (int i = 0; i < 8; ++i) {
        acc[i] += __shfl_xor(acc[i], 16);
        acc[i] += __shfl_xor(acc[i], 32);
    }
    if (g == 0) {
        float w = rs_in[node];
        uint4 o;
        o.x = pack2bf(acc[0] * w, acc[1] * w);
        o.y = pack2bf(acc[2] * w, acc[3] * w);
        o.z = pack2bf(acc[4] * w, acc[5] * w);
        o.w = pack2bf(acc[6] * w, acc[7] * w);
        yb4[(size_t)node * 16 + sub] = o;
    }
}

// ---------------- stage Wt (32KB) into LDS with padded stride ----------------
__device__ inline void stage_wt(const uint4* __restrict__ Wt4, unsigned int* WtL, int t) {
#pragma unroll
    for (int i = 0; i < 8; ++i) {
        int q = t + 256 * i;           // 0..2047
        int row = q >> 4, col4 = q & 15;
        *(uint4*)&WtL[row * WTP + col4 * 4] = Wt4[q];
    }
}

// ---------------- layer-1 MM: x1b = bf16( relu(A@W1+b1) * rs_out[row] ) ----------------
__global__ __launch_bounds__(256) void mm_mfma(const unsigned char* __restrict__ A,
                                               const uint4* __restrict__ Wt4,
                                               const float* __restrict__ bias,
                                               const float* __restrict__ rs_out,
                                               unsigned short* __restrict__ out, int n) {
    __shared__ unsigned int WtL[128 * WTP];   // 34.8 KB
    int t = threadIdx.x;
    stage_wt(Wt4, WtL, t);
    int wave = t >> 6, lane = t & 63;
    int m = lane & 15, q = lane >> 4;
    int r0 = (int)blockIdx.x * 64 + wave * 16;
    int arow = min(r0 + m, n - 1);
    __syncthreads();
    f4v acc[8];
#pragma unroll
    for (int c = 0; c < 8; ++c) acc[c] = (f4v){0.f, 0.f, 0.f, 0.f};
#pragma unroll
    for (int k0 = 0; k0 < 4; ++k0) {
        s8v a = *(const s8v*)(A + (size_t)arow * 256 + k0 * 64 + q * 16);
#pragma unroll
        for (int c = 0; c < 8; ++c) {
            s8v b = *(const s8v*)&WtL[(c * 16 + m) * WTP + k0 * 16 + q * 4];
            acc[c] = __builtin_amdgcn_mfma_f32_16x16x32_bf16(a, b, acc[c], 0, 0, 0);
        }
    }
#pragma unroll
    for (int c = 0; c < 8; ++c) {
        float bv = bias[c * 16 + m];
#pragma unroll
        for (int r = 0; r < 4; ++r) {
            int row = r0 + q * 4 + r;
            if (row < n) {
                float val = fmaxf(acc[c][r] + bv, 0.0f);
                out[(size_t)row * 128 + c * 16 + m] = f2bf(val * rs_out[row]);
            }
        }
    }
}

// ---------------- layer-2 MM with FUSED mean-readout numerator (LDS Wt too) ----------------
__global__ __launch_bounds__(256) void mm_mfma_readout(const unsigned char* __restrict__ A,
                                                       const uint4* __restrict__ Wt4,
                                                       const float* __restrict__ bias,
                                                       const int* __restrict__ gid,
                                                       float* __restrict__ hg, int n) {
    __shared__ unsigned int WtL[128 * WTP];   // 34.8 KB
    __shared__ float hgloc[HL][DIM];          // 2 KB
    int t = threadIdx.x;
    stage_wt(Wt4, WtL, t);
    for (int i = t; i < HL * DIM; i += 256) ((float*)hgloc)[i] = 0.0f;
    int wave = t >> 6, lane = t & 63;
    int m = lane & 15, q = lane >> 4;
    int r0 = (int)blockIdx.x * 64 + wave * 16;
    int b0 = (int)blockIdx.x * 64;
    int gid0 = gid[min(b0, n - 1)];
    int arow = min(r0 + m, n - 1);
    __syncthreads();
    f4v acc[8];
#pragma unroll
    for (int c = 0; c < 8; ++c) acc[c] = (f4v){0.f, 0.f, 0.f, 0.f};
#pragma unroll
    for (int k0 = 0; k0 < 4; ++k0) {
        s8v a = *(const s8v*)(A + (size_t)arow * 256 + k0 * 64 + q * 16);
#pragma unroll
        for (int c = 0; c < 8; ++c) {
            s8v b = *(const s8v*)&WtL[(c * 16 + m) * WTP + k0 * 16 + q * 4];
            acc[c] = __builtin_amdgcn_mfma_f32_16x16x32_bf16(a, b, acc[c], 0, 0, 0);
        }
    }
    int gfirst = gid[min(r0, n - 1)];
    int glast = gid[min(r0 + 15, n - 1)];
    bool uni = (gfirst == glast) && (r0 + 15 < n);
    if (uni) {
        int gl = gfirst - gid0;
#pragma unroll
        for (int c = 0; c < 8; ++c) {
            float bv = bias[c * 16 + m];
            float s = fmaxf(acc[c][0] + bv, 0.0f) + fmaxf(acc[c][1] + bv, 0.0f) +
                      fmaxf(acc[c][2] + bv, 0.0f) + fmaxf(acc[c][3] + bv, 0.0f);
            s += __shfl_xor(s, 16);
            s += __shfl_xor(s, 32);
            if (q == 0) {
                if (gl < HL)
                    atomicAdd(&hgloc[gl][c * 16 + m], s);
                else
                    atomicAdd(&hg[(size_t)gfirst * DIM + c * 16 + m], s);
            }
        }
    } else {
#pragma unroll
        for (int r = 0; r < 4; ++r) {
            int row = r0 + q * 4 + r;
            if (row < n) {
                int g = gid[row];
                int gl = g - gid0;
#pragma unroll
                for (int c = 0; c < 8; ++c) {
                    float val = fmaxf(acc[c][r] + bias[c * 16 + m], 0.0f);
                    if (gl < HL)
                        atomicAdd(&hgloc[gl][c * 16 + m], val);
                    else
                        atomicAdd(&hg[(size_t)g * DIM + c * 16 + m], val);
                }
            }
        }
    }
    __syncthreads();
    for (int i = t; i < HL * DIM; i += 256) {
        float v = ((float*)hgloc)[i];
        int g = gid0 + (i >> 7);
        if (v != 0.0f && g < NG) atomicAdd(&hg[(size_t)g * DIM + (i & 127)], v);
    }
}

// ---------------- classifier: one block per graph, fused count ----------------
__global__ void classify_kernel(const float* __restrict__ hg, const int* __restrict__ gid,
                                const float* __restrict__ Wc, const float* __restrict__ bc,
                                float* __restrict__ out, int n) {
    __shared__ float inv;
    int g = blockIdx.x, t = threadIdx.x;
    if (t == 0) {
        int lo = 0, hi = n;
        while (lo < hi) { int mid = (lo + hi) >> 1; if (gid[mid] < g) lo = mid + 1; else hi = mid; }
        int lb = lo;
        lo = 0; hi = n;
        while (lo < hi) { int mid = (lo + hi) >> 1; if (gid[mid] <= g) lo = mid + 1; else hi = mid; }
        inv = 1.0f / fmaxf((float)(lo - lb), 1.0f);
    }
    __syncthreads();
    if (t < NCLS) {
        float s = 0.0f;
        for (int k = 0; k < DIM; ++k) s = fmaf(hg[g * DIM + k], Wc[k * NCLS + t], s);
        out[g * NCLS + t] = s * inv + bc[t];
    }
}

extern "C" void kernel_launch(void* const* d_in, const int* in_sizes, int n_in,
                              void* d_out, int out_size, void* d_ws, size_t ws_size,
                              hipStream_t stream) {
    const float* h   = (const float*)d_in[0];
    const int*   src = (const int*)d_in[1];
    const int*   dst = (const int*)d_in[2];
    const int*   gid = (const int*)d_in[3];
    const float* W1  = (const float*)d_in[4];
    const float* b1  = (const float*)d_in[5];
    const float* W2  = (const float*)d_in[6];
    const float* b2  = (const float*)d_in[7];
    const float* Wc  = (const float*)d_in[8];
    const float* bc  = (const float*)d_in[9];
    float* out = (float*)d_out;

    const int n = in_sizes[0] / DIM;   // 100000
    const int e = in_sizes[1];         // 1600000
    const int nw = (n + WSZ - 1) / WSZ;   // 391 windows

    char* ws = (char*)d_ws;
    size_t off = 0;
    auto alloc = [&](size_t bytes) -> char* {
        char* p = ws + off;
        off = (off + bytes + 255) & ~(size_t)255;
        return p;
    };
    int*   cnt_in  = (int*)alloc((size_t)n * 4);
    float* rs_in   = (float*)alloc((size_t)n * 4);
    float* rs_out  = (float*)alloc((size_t)n * 4);
    int*   curD    = (int*)alloc((size_t)NWMAX * 4);
    int*   curS    = (int*)alloc((size_t)NWMAX * 4);
    int*   colx_pad = (int*)alloc((size_t)n * CAP * 4);          // 25.6 MB
    int*   bucketD = (int*)alloc((size_t)nw * CAPB * 4);         // 12.8 MB
    unsigned char* bucketS = (unsigned char*)alloc((size_t)nw * CAPB);  // 3.2 MB
    float* hg      = (float*)alloc((size_t)NG * DIM * 4);
    unsigned short* Wt1 = (unsigned short*)alloc(128 * 128 * 2);
    unsigned short* Wt2 = (unsigned short*)alloc(128 * 128 * 2);
    uint4* hb4  = (uint4*)alloc((size_t)(n + 4) * 64 * 4);
    uint4* aggB = (uint4*)alloc((size_t)(n + 4) * 64 * 4);
    uint4* x1b4 = (uint4*)alloc((size_t)(n + 4) * 64 * 4);

    const int SPMM_B = (n + 3) / 4;
    const int MM_B = (n + 63) / 64;
    const int AB = (e + EPB - 1) / EPB;

    prep_kernel<<<128, 256, 0, stream>>>(W1, W2, Wt1, Wt2, curD, curS, hb4, x1b4, hg, nw, n);
    bucket_kernel<<<AB, 1024, 0, stream>>>(src, dst, curD, curS, bucketD, bucketS, e, nw);
    window_kernel<<<nw, 512, 0, stream>>>(curD, curS, bucketD, bucketS, h,
                                          cnt_in, rs_in, rs_out, colx_pad, hb4, n);

    // layer 1
    spmm_bf16<<<SPMM_B, 256, 0, stream>>>(hb4, cnt_in, colx_pad, rs_in, aggB, n);
    mm_mfma<<<MM_B, 256, 0, stream>>>((const unsigned char*)aggB, (const uint4*)Wt1,
                                      b1, rs_out, (unsigned short*)x1b4, n);
    // layer 2 + fused readout numerator
    spmm_bf16<<<SPMM_B, 256, 0, stream>>>(x1b4, cnt_in, colx_pad, rs_in, aggB, n);
    mm_mfma_readout<<<MM_B, 256, 0, stream>>>((const unsigned char*)aggB, (const uint4*)Wt2,
                                              b2, gid, hg, n);
    // classify (fused per-graph count)
    classify_kernel<<<NG, 64, 0, stream>>>(hg, gid, Wc, bc, out, n);
}